// Round 18
// baseline (478.497 us; speedup 1.0000x reference)
//
#include <hip/hip_runtime.h>
#include <hip/hip_fp16.h>
#include <math.h>

// CSR build tunables. Coarse bucket = 2048 nodes (cshift=11, ncb=98 for n=200k).
#define MAXCB 128        // max coarse buckets
#define MAXW 4096        // max nodes per coarse bucket supported by LDS
#define TILE1 8192       // edges per scatter tile
#define SCAT_T 512
#define EPT1 (TILE1 / SCAT_T)
#define GCHUNK 4096      // gather_tpn col-chunk (16 KB LDS)
#define CNT_BLKS 1024    // bin_count histogram blocks (then prep_w blocks)

typedef _Float16 f16x8 __attribute__((ext_vector_type(8)));
typedef float f32x4 __attribute__((ext_vector_type(4)));

// ---------------- fp16 pack helpers ----------------

__device__ __forceinline__ unsigned int pack_f16(float a, float b) {
    __half2 h = __floats2half2_rn(a, b);
    return *reinterpret_cast<unsigned int*>(&h);
}
__device__ __forceinline__ float f16_lo(unsigned int u) {
    __half2 h = *reinterpret_cast<__half2*>(&u);
    return __low2float(h);
}
__device__ __forceinline__ float f16_hi(unsigned int u) {
    __half2 h = *reinterpret_cast<__half2*>(&u);
    return __high2float(h);
}
__device__ __forceinline__ void acc8(float* a, uint4 u) {
    a[0] += f16_lo(u.x); a[1] += f16_hi(u.x);
    a[2] += f16_lo(u.y); a[3] += f16_hi(u.y);
    a[4] += f16_lo(u.z); a[5] += f16_hi(u.z);
    a[6] += f16_lo(u.w); a[7] += f16_hi(u.w);
}
__device__ __forceinline__ void unpack8(uint4 u, float* v) {
    v[0] = f16_lo(u.x); v[1] = f16_hi(u.x);
    v[2] = f16_lo(u.y); v[3] = f16_hi(u.y);
    v[4] = f16_lo(u.z); v[5] = f16_hi(u.z);
    v[6] = f16_lo(u.w); v[7] = f16_hi(u.w);
}
__device__ __forceinline__ uint4 h2add4(uint4 a, uint4 b) {
    const __half2* pa = reinterpret_cast<const __half2*>(&a);
    const __half2* pb = reinterpret_cast<const __half2*>(&b);
    uint4 r;
    __half2* pr = reinterpret_cast<__half2*>(&r);
#pragma unroll
    for (int i = 0; i < 4; i++) pr[i] = __hadd2(pa[i], pb[i]);
    return r;
}
__device__ __forceinline__ unsigned int pkadd(unsigned int a, unsigned int b) {
    __half2 r = __hadd2(*reinterpret_cast<__half2*>(&a), *reinterpret_cast<__half2*>(&b));
    return *reinterpret_cast<unsigned int*>(&r);
}

// ---------------- inline edge dtype detection (int32 vs int64) ----------------

__device__ __forceinline__ bool detect64(const int* __restrict__ ei) {
    int lane = threadIdx.x & 63;
    unsigned long long m = __ballot(ei[2 * lane + 1] != 0);
    return m == 0ull;
}

__device__ __forceinline__ int load_src(const int* ei, int e, bool is64, int i) {
    return is64 ? ei[2 * i] : ei[i];
}
__device__ __forceinline__ int load_dst(const int* ei, int e, bool is64, int i) {
    return is64 ? ei[2 * e + 2 * i] : ei[e + i];
}

// ---------------- pass 1: per-coarse-bucket edge counts (+fused weight prep) -------
// Blocks >= CNT_BLKS convert/transpose the weights to fp16 W^T instead
// (saves a launch; independent work).
// wt layout: [96][128] (W1|Wsk02) at 0; [48][64] (W2|Wsk13) at 12288;
// [16][32] (W3) at 15360. Row-major [col][k].

__global__ __launch_bounds__(256) void bin_count(const int* __restrict__ ei, int e,
                                                 int cshift, int* __restrict__ gcnt,
                                                 const float* __restrict__ W1,
                                                 const float* __restrict__ Wsk02,
                                                 const float* __restrict__ W2,
                                                 const float* __restrict__ Wsk13,
                                                 const float* __restrict__ W3,
                                                 unsigned short* __restrict__ wt) {
    if (blockIdx.x >= CNT_BLKS) {
        int i = (blockIdx.x - CNT_BLKS) * 256 + threadIdx.x;
        float v;
        if (i < 12288) {
            int c = i >> 7, k = i & 127;
            v = (c < 64) ? W1[k * 64 + c] : Wsk02[k * 32 + (c - 64)];
        } else if (i < 15360) {
            int j = i - 12288;
            int c = j >> 6, k = j & 63;
            v = (c < 32) ? W2[k * 32 + c] : Wsk13[k * 16 + (c - 32)];
        } else if (i < 15872) {
            int j = i - 15360;
            int c = j >> 5, k = j & 31;
            v = W3[k * 16 + c];
        } else return;
        wt[i] = (unsigned short)pack_f16(v, 0.f);
        return;
    }
    __shared__ int h[MAXCB];
    for (int i = threadIdx.x; i < MAXCB; i += 256) h[i] = 0;
    bool is64 = detect64(ei);
    __syncthreads();
    int stride = CNT_BLKS * 256;
    for (int i = blockIdx.x * 256 + threadIdx.x; i < e; i += stride) {
        int d = load_dst(ei, e, is64, i);
        atomicAdd(&h[d >> cshift], 1);
    }
    __syncthreads();
    for (int i = threadIdx.x; i < MAXCB; i += 256)
        if (h[i]) atomicAdd(&gcnt[i], h[i]);
}

// ---------------- pass 2: scan coarse counts; init cursors ----------------

__global__ void bin_scan_init(const int* __restrict__ gcnt, int ncb,
                              int* __restrict__ cbase, int* __restrict__ gcur1) {
    __shared__ int sh[MAXCB];
    int t = threadIdx.x;
    int v = (t < ncb) ? gcnt[t] : 0;
    sh[t] = v;
    __syncthreads();
    for (int off = 1; off < MAXCB; off <<= 1) {
        int x = (t >= off) ? sh[t - off] : 0;
        __syncthreads();
        sh[t] += x;
        __syncthreads();
    }
    if (t < ncb) {
        int excl = sh[t] - v;
        cbase[t] = excl;
        gcur1[t] = excl;
        if (t == ncb - 1) cbase[ncb] = sh[t];
    }
}

// ---------------- pass 3: tile-sort into coarse buckets ----------------
// pk = (src << cshift) | (dst & (2^cshift - 1)).

__global__ __launch_bounds__(SCAT_T) void scatter_coarse(const int* __restrict__ ei, int e,
                                                         int cshift,
                                                         int* __restrict__ gcur1,
                                                         unsigned int* __restrict__ gpk1) {
    __shared__ int hist[MAXCB];
    __shared__ int lbase[MAXCB];
    __shared__ int delta[MAXCB];
    __shared__ int cur[MAXCB];
    __shared__ unsigned int sbuf[TILE1];
    __shared__ unsigned char sbkt[TILE1];
    __shared__ int sh[SCAT_T];

    const int t = threadIdx.x;
    const int pkmask = (1 << cshift) - 1;
    const bool is64 = detect64(ei);
    const int tile0 = blockIdx.x * TILE1;
    const int cnt = min(TILE1, e - tile0);

    for (int i = t; i < MAXCB; i += SCAT_T) hist[i] = 0;
    __syncthreads();

    unsigned int pk[EPT1];
    int bk[EPT1];
#pragma unroll
    for (int k = 0; k < EPT1; k++) {
        int g = tile0 + k * SCAT_T + t;
        bk[k] = -1;
        if (g < e) {
            int s = load_src(ei, e, is64, g);
            int d = load_dst(ei, e, is64, g);
            pk[k] = ((unsigned int)s << cshift) | (unsigned int)(d & pkmask);
            bk[k] = d >> cshift;
            atomicAdd(&hist[bk[k]], 1);
        }
    }
    __syncthreads();

    {
        int v = (t < MAXCB) ? hist[t] : 0;
        sh[t] = v;
        __syncthreads();
        for (int off = 1; off < SCAT_T; off <<= 1) {
            int x = (t >= off) ? sh[t - off] : 0;
            __syncthreads();
            sh[t] += x;
            __syncthreads();
        }
        if (t < MAXCB) lbase[t] = sh[t] - v;
    }
    __syncthreads();

    if (t < MAXCB) {
        int c = hist[t];
        if (c > 0) delta[t] = atomicAdd(&gcur1[t], c) - lbase[t];
        cur[t] = lbase[t];
    }
    __syncthreads();

#pragma unroll
    for (int k = 0; k < EPT1; k++) {
        if (bk[k] >= 0) {
            int p = atomicAdd(&cur[bk[k]], 1);
            sbuf[p] = pk[k];
            sbkt[p] = (unsigned char)bk[k];
        }
    }
    __syncthreads();

    for (int i = t; i < cnt; i += SCAT_T)
        gpk1[delta[sbkt[i]] + i] = sbuf[i];
}

// ---------------- pass 4 (R18 merged): dinv + row_ptr + col per COARSE bucket ------
// Replaces R17's scatter_fine + bucket_build (eliminates the gpk2 write+read
// roundtrip, one LDS sort, and a launch). Direct col scatter is L2-friendly:
// each coarse bucket's col window is ~260 KB (~12 windows/XCD = 3 MB < 4 MB
// L2), so random 4B writes are absorbed and written back as full lines.
// Pass 1 histograms per-node degrees (width<=4096 LDS bins); scan gives
// row_ptr + dinv + LDS cursors; pass 2 re-reads the L2-warm gpk slice and
// scatters col to final position.

__global__ __launch_bounds__(1024) void bucket_build_coarse(
    const unsigned int* __restrict__ gpk, const int* __restrict__ cbase,
    int cshift, int n, int e, float* __restrict__ dinv,
    int* __restrict__ row_ptr, int* __restrict__ col) {
    __shared__ int dc[MAXW];
    __shared__ int cur[MAXW];
    __shared__ int sh[1024];
    const int t = threadIdx.x;
    const int b = blockIdx.x;
    const int width = 1 << cshift;
    const int mask = width - 1;
    const int node0 = b << cshift;
    const int nc = min(width, n - node0);
    const int lo = cbase[b], hi = cbase[b + 1];

    for (int i = t; i < width; i += 1024) dc[i] = 0;
    __syncthreads();
    for (int j = lo + t; j < hi; j += 1024)
        atomicAdd(&dc[gpk[j] & mask], 1);
    __syncthreads();

    {
        const int E = width >> 10;   // entries per thread (1,2,4)
        int v[4] = {0, 0, 0, 0};
        int s = 0;
        int b0 = t * E;
#pragma unroll 4
        for (int q = 0; q < 4; q++)
            if (q < E) { v[q] = dc[b0 + q]; s += v[q]; }
        sh[t] = s;
        __syncthreads();
        for (int off = 1; off < 1024; off <<= 1) {
            int x = (t >= off) ? sh[t - off] : 0;
            __syncthreads();
            sh[t] += x;
            __syncthreads();
        }
        int excl = sh[t] - s;
#pragma unroll 4
        for (int q = 0; q < 4; q++) {
            if (q < E) {
                int i = b0 + q;
                if (i < nc) {
                    row_ptr[node0 + i] = lo + excl;
                    dinv[node0 + i] = rsqrtf(1.0f + (float)v[q]);
                }
                cur[i] = excl;
                excl += v[q];
            }
        }
    }
    if (b == gridDim.x - 1 && t == 0) row_ptr[n] = e;
    __syncthreads();

    for (int j = lo + t; j < hi; j += 1024) {
        unsigned int pv = gpk[j];
        int p = atomicAdd(&cur[pv & mask], 1);
        col[lo + p] = (int)(pv >> cshift);
    }
}

// ---------------- MFMA GEMM (R13 core; fp16-packed out1/out2) ----------------

template <int K, int CO1, int CO2, bool AHALF>
__global__ __launch_bounds__(256) void gemm_mfma(const void* __restrict__ Av,
                                                 const unsigned short* __restrict__ wt,
                                                 const float* __restrict__ dinv,
                                                 unsigned int* __restrict__ out1,
                                                 unsigned int* __restrict__ out2, int n) {
    constexpr int N = CO1 + CO2;
    constexpr int NCT = N / 16;
    constexpr int NK = K / 32;
    constexpr int CHK = K / 8;
    constexpr int SWZ = (CHK - 1) < 15 ? (CHK - 1) : 15;
    __shared__ __align__(16) unsigned char Ash[64 * K * 2];
    __shared__ __align__(16) unsigned char Bsh[N * K * 2];

    const int t = threadIdx.x;
    const int row0 = blockIdx.x * 64;

    for (int i = t; i < 64 * CHK; i += 256) {
        int r = i / CHK, c = i % CHK;
        int row = row0 + r;
        uint4 w{0u, 0u, 0u, 0u};
        if (row < n) {
            if (AHALF) {
                w = *reinterpret_cast<const uint4*>(
                    (const unsigned short*)Av + (size_t)row * K + c * 8);
            } else {
                const float* xr = (const float*)Av + (size_t)row * K + c * 8;
                float4 p = *reinterpret_cast<const float4*>(xr);
                float4 q = *reinterpret_cast<const float4*>(xr + 4);
                w.x = pack_f16(p.x, p.y); w.y = pack_f16(p.z, p.w);
                w.z = pack_f16(q.x, q.y); w.w = pack_f16(q.z, q.w);
            }
        }
        int addr = i * 16;
        addr ^= ((r & SWZ) << 4);
        *reinterpret_cast<uint4*>(&Ash[addr]) = w;
    }
    for (int i = t; i < N * CHK; i += 256) {
        int cc = i / CHK;
        uint4 w = *reinterpret_cast<const uint4*>(&wt[(i / CHK) * K + (i % CHK) * 8]);
        int addr = i * 16;
        addr ^= ((cc & SWZ) << 4);
        *reinterpret_cast<uint4*>(&Bsh[addr]) = w;
    }
    __syncthreads();

    const int wv = t >> 6;
    const int lane = t & 63;
    const int lrow = wv * 16 + (lane & 15);
    const int kb = (lane >> 4) * 16;

    f16x8 afr[NK];
#pragma unroll
    for (int s = 0; s < NK; s++) {
        int addr = lrow * (2 * K) + s * 64 + kb;
        addr ^= ((lrow & SWZ) << 4);
        afr[s] = *reinterpret_cast<const f16x8*>(&Ash[addr]);
    }

    f32x4 acc[NCT];
#pragma unroll
    for (int ct = 0; ct < NCT; ct++) acc[ct] = f32x4{0.f, 0.f, 0.f, 0.f};

#pragma unroll
    for (int ct = 0; ct < NCT; ct++) {
        int cc = ct * 16 + (lane & 15);
#pragma unroll
        for (int s = 0; s < NK; s++) {
            int addr = cc * (2 * K) + s * 64 + kb;
            addr ^= ((cc & SWZ) << 4);
            f16x8 bfr = *reinterpret_cast<const f16x8*>(&Bsh[addr]);
            acc[ct] = __builtin_amdgcn_mfma_f32_16x16x32_f16(afr[s], bfr, acc[ct], 0, 0, 0);
        }
    }

    const int rbase = row0 + wv * 16 + (lane >> 4) * 4;
    const int cidx = lane & 15;
    float dn[4];
#pragma unroll
    for (int r = 0; r < 4; r++) dn[r] = (rbase + r < n) ? dinv[rbase + r] : 0.f;

#pragma unroll
    for (int ct = 0; ct < NCT; ct++) {
        int col = ct * 16 + cidx;
        if (col < CO1) {
#pragma unroll
            for (int r = 0; r < 4; r++) {
                float v = acc[ct][r] * dn[r];
                float o = __shfl_xor(v, 1);
                int row = rbase + r;
                if (!(lane & 1) && row < n)
                    out1[(size_t)row * (CO1 / 2) + ct * 8 + cidx / 2] = pack_f16(v, o);
            }
        } else if (CO2 > 0) {
#pragma unroll
            for (int r = 0; r < 4; r++) {
                float v = acc[ct][r];
                float o = __shfl_xor(v, 1);
                int row = rbase + r;
                if (!(lane & 1) && row < n)
                    out2[(size_t)row * (CO2 / 2) + (ct * 16 + cidx - CO1) / 2] =
                        pack_f16(v, o);
            }
        }
    }
}

// ---------------- Wave-based gather for F=64 (at fabric floor) ----------------

template <int F, bool PACKOUT>
__global__ __launch_bounds__(256) void gather_combine(
    const uint4* __restrict__ hp4, const int* __restrict__ row_ptr,
    const int* __restrict__ col, const float* __restrict__ dinv,
    const float* __restrict__ bias, void* __restrict__ outv, int n) {
    constexpr int L = F / 8;
    constexpr int EPW = 64 / L;
    int wid = (blockIdx.x * blockDim.x + threadIdx.x) >> 6;
    int lane = threadIdx.x & 63;
    if (wid >= n) return;
    int s = lane / L;
    int el = lane % L;
    int start = row_ptr[wid];
    int end = row_ptr[wid + 1];

    float a[8] = {0.f, 0.f, 0.f, 0.f, 0.f, 0.f, 0.f, 0.f};
    const uint4 z4{0u, 0u, 0u, 0u};
    for (int j = start + s; j < end; j += 4 * EPW) {
        int j1 = j + EPW, j2 = j + 2 * EPW, j3 = j + 3 * EPW;
        bool v1 = j1 < end, v2 = j2 < end, v3 = j3 < end;
        int c0 = col[j];
        int c1 = col[v1 ? j1 : j];
        int c2 = col[v2 ? j2 : j];
        int c3 = col[v3 ? j3 : j];
        uint4 u0 = hp4[(size_t)c0 * L + el];
        uint4 u1 = hp4[(size_t)c1 * L + el];
        uint4 u2 = hp4[(size_t)c2 * L + el];
        uint4 u3 = hp4[(size_t)c3 * L + el];
        if (!v1) u1 = z4;
        if (!v2) u2 = z4;
        if (!v3) u3 = z4;
        uint4 t01 = h2add4(u0, u1);
        uint4 t23 = h2add4(u2, u3);
        acc8(a, h2add4(t01, t23));
    }

#pragma unroll
    for (int m = L; m < 64; m <<= 1) {
#pragma unroll
        for (int q = 0; q < 8; q++) a[q] += __shfl_xor(a[q], m);
    }

    if (lane < L) {
        float dn = dinv[wid];
        uint4 us = hp4[(size_t)wid * L + el];
        float v[8];
        unpack8(us, v);
        float4 b0 = *reinterpret_cast<const float4*>(&bias[8 * el]);
        float4 b1 = *reinterpret_cast<const float4*>(&bias[8 * el + 4]);
        float o[8];
        o[0] = dn * a[0] + v[0] * dn + b0.x;
        o[1] = dn * a[1] + v[1] * dn + b0.y;
        o[2] = dn * a[2] + v[2] * dn + b0.z;
        o[3] = dn * a[3] + v[3] * dn + b0.w;
        o[4] = dn * a[4] + v[4] * dn + b1.x;
        o[5] = dn * a[5] + v[5] * dn + b1.y;
        o[6] = dn * a[6] + v[6] * dn + b1.z;
        o[7] = dn * a[7] + v[7] * dn + b1.w;
#pragma unroll
        for (int q = 0; q < 8; q++) o[q] = fmaxf(o[q], 0.f);
        if (PACKOUT) {
            uint4 pk{pack_f16(o[0], o[1]), pack_f16(o[2], o[3]),
                     pack_f16(o[4], o[5]), pack_f16(o[6], o[7])};
            ((uint4*)outv)[(size_t)wid * L + el] = pk;
        } else {
            float* out = (float*)outv;
            float4 w0{o[0], o[1], o[2], o[3]};
            float4 w1{o[4], o[5], o[6], o[7]};
            *reinterpret_cast<float4*>(&out[(size_t)wid * F + 8 * el]) = w0;
            *reinterpret_cast<float4*>(&out[(size_t)wid * F + 8 * el + 4]) = w1;
        }
    }
}

// ---------------- Multi-thread-per-node gather for F=16/32 (T=8, fp16 sk) ----------

template <int F, int T, bool FINAL, bool PACKOUT>
__global__ __launch_bounds__(256) void gather_tpn(
    const uint4* __restrict__ hp4, const int* __restrict__ row_ptr,
    const int* __restrict__ col, const float* __restrict__ dinv,
    const float* __restrict__ bias, const uint4* __restrict__ skh,
    const float* __restrict__ bsk, void* __restrict__ outv,
    const float* __restrict__ Wlin, const float* __restrict__ blin, int n) {
    constexpr int L = F / 8;       // uint4 words per row
    constexpr int NPB = 256 / T;   // nodes per block
    __shared__ int lcol[GCHUNK];
    const int t = threadIdx.x;
    const int sub = t & (T - 1);
    const int node0 = blockIdx.x * NPB;
    const int node = node0 + (t / T);
    const int hiN = min(node0 + NPB, n);
    const int lo = row_ptr[node0];
    const int hi = row_ptr[hiN];

    int start = 0, end = 0;
    if (node < n) { start = row_ptr[node]; end = row_ptr[node + 1]; }

    unsigned int acc[F / 2];
#pragma unroll
    for (int q = 0; q < F / 2; q++) acc[q] = 0u;

    for (int ch = lo; ch < hi; ch += GCHUNK) {
        int cnt = min(GCHUNK, hi - ch);
        __syncthreads();
        for (int i = t; i < cnt; i += 256) lcol[i] = col[ch + i];
        __syncthreads();
        int first = start + sub;
        if (first < ch) first += ((ch - first + T - 1) & ~(T - 1));
        int last = min(end, ch + cnt);
        int j = first;
        if (j < last) {
            uint4 u[L];
            {
                const uint4* rp = hp4 + (size_t)lcol[j - ch] * L;
#pragma unroll
                for (int w = 0; w < L; w++) u[w] = rp[w];
            }
            for (j += T; j < last; j += T) {
                uint4 v[L];
                const uint4* rq = hp4 + (size_t)lcol[j - ch] * L;
#pragma unroll
                for (int w = 0; w < L; w++) v[w] = rq[w];   // next row in flight
#pragma unroll
                for (int w = 0; w < L; w++) {
                    acc[4 * w + 0] = pkadd(acc[4 * w + 0], u[w].x);
                    acc[4 * w + 1] = pkadd(acc[4 * w + 1], u[w].y);
                    acc[4 * w + 2] = pkadd(acc[4 * w + 2], u[w].z);
                    acc[4 * w + 3] = pkadd(acc[4 * w + 3], u[w].w);
                }
#pragma unroll
                for (int w = 0; w < L; w++) u[w] = v[w];
            }
#pragma unroll
            for (int w = 0; w < L; w++) {
                acc[4 * w + 0] = pkadd(acc[4 * w + 0], u[w].x);
                acc[4 * w + 1] = pkadd(acc[4 * w + 1], u[w].y);
                acc[4 * w + 2] = pkadd(acc[4 * w + 2], u[w].z);
                acc[4 * w + 3] = pkadd(acc[4 * w + 3], u[w].w);
            }
        }
    }

    // combine the T sub-thread partials
#pragma unroll
    for (int m = 1; m < T; m <<= 1) {
#pragma unroll
        for (int q = 0; q < F / 2; q++) {
            unsigned int o = (unsigned int)__shfl_xor((int)acc[q], m);
            acc[q] = pkadd(acc[q], o);
        }
    }

    if (node < n && sub == 0) {
        float dn = dinv[node];
        const uint4* sp = hp4 + (size_t)node * L;
        float o[F];
#pragma unroll
        for (int w = 0; w < L; w++) {
            uint4 u = sp[w];
            float sv[8];
            unpack8(u, sv);
#pragma unroll
            for (int q = 0; q < 8; q++) {
                int f = w * 8 + q;
                float av = (q & 1) ? f16_hi(acc[4 * w + (q >> 1)])
                                   : f16_lo(acc[4 * w + (q >> 1)]);
                o[f] = dn * (av + sv[q]) + bias[f];
            }
        }
        if (skh) {
            const uint4* skp = skh + (size_t)node * L;
#pragma unroll
            for (int w = 0; w < L; w++) {
                float sv2[8];
                unpack8(skp[w], sv2);
#pragma unroll
                for (int q = 0; q < 8; q++)
                    o[w * 8 + q] += sv2[q] + bsk[w * 8 + q];
            }
        }
#pragma unroll
        for (int f = 0; f < F; f++) o[f] = fmaxf(o[f], 0.f);

        if (FINAL) {
            float d = blin[0];
#pragma unroll
            for (int f = 0; f < F; f++) d += o[f] * Wlin[f];
            ((float*)outv)[node] = 1.0f / (1.0f + expf(-d));
        } else if (PACKOUT) {
            uint4* o4 = (uint4*)outv + (size_t)node * L;
#pragma unroll
            for (int w = 0; w < L; w++) {
                uint4 pk{pack_f16(o[w * 8 + 0], o[w * 8 + 1]),
                         pack_f16(o[w * 8 + 2], o[w * 8 + 3]),
                         pack_f16(o[w * 8 + 4], o[w * 8 + 5]),
                         pack_f16(o[w * 8 + 6], o[w * 8 + 7])};
                o4[w] = pk;
            }
        }
    }
}

// ---------------- launch ----------------

extern "C" void kernel_launch(void* const* d_in, const int* in_sizes, int n_in,
                              void* d_out, int out_size, void* d_ws, size_t ws_size,
                              hipStream_t stream) {
    const float* x     = (const float*)d_in[0];
    const int*   ei    = (const int*)d_in[1];
    const float* W1    = (const float*)d_in[2];
    const float* b1    = (const float*)d_in[3];
    const float* W2    = (const float*)d_in[4];
    const float* b2    = (const float*)d_in[5];
    const float* W3    = (const float*)d_in[6];
    const float* b3    = (const float*)d_in[7];
    const float* Wsk02 = (const float*)d_in[8];
    const float* bsk02 = (const float*)d_in[9];
    const float* Wsk13 = (const float*)d_in[10];
    const float* bsk13 = (const float*)d_in[11];
    const float* Wlin  = (const float*)d_in[12];
    const float* blin  = (const float*)d_in[13];

    const int n = in_sizes[0] / 128;
    const int e = in_sizes[1] / 2;

    // coarse bucket shift: 2048 nodes; grow if n exceeds MAXCB buckets
    // (width capped at MAXW by LDS — holds for n <= 512k).
    int cshift = 11;
    while (((n + (1 << cshift) - 1) >> cshift) > MAXCB) cshift++;
    const int ncb = (n + (1 << cshift) - 1) >> cshift;

    // workspace carve (256B aligned)
    char* p = (char*)d_ws;
    auto alloc = [&](size_t bytes) {
        void* r = (void*)p;
        p += (bytes + 255) / 256 * 256;
        return r;
    };
    int*   gcnt    = (int*)alloc(MAXCB * 4);
    int*   cbase   = (int*)alloc((MAXCB + 1) * 4);
    int*   gcur1   = (int*)alloc(MAXCB * 4);
    unsigned short* wt = (unsigned short*)alloc(15872 * 2);
    int*   row_ptr = (int*)alloc((size_t)(n + 1) * 4);
    float* dinv    = (float*)alloc((size_t)n * 4);
    int*   col     = (int*)alloc((size_t)e * 4);
    size_t h1b     = (size_t)e * 4 > (size_t)n * 128 ? (size_t)e * 4 : (size_t)n * 128;
    unsigned int* h1 = (unsigned int*)alloc(h1b);
    unsigned int* h2 = (unsigned int*)alloc((size_t)n * 64);
    unsigned int* sk02 = (unsigned int*)alloc((size_t)n * 64);   // fp16 x@Wsk02
    unsigned int* sk13 = (unsigned int*)alloc((size_t)n * 32);   // fp16 h1@Wsk13
    unsigned int* preb = (unsigned int*)alloc((size_t)n * 128);  // fp16 gather table
    unsigned int* gpk1 = h1;   // coarse-sorted packed edges; dead before gather1 writes h1

    auto cdiv = [](int a, int b) { return (a + b - 1) / b; };

    // CSR build: count(+prep_w) -> scan -> coarse sort -> merged build
    hipMemsetAsync(gcnt, 0, MAXCB * 4, stream);
    bin_count<<<CNT_BLKS + 62, 256, 0, stream>>>(ei, e, cshift, gcnt,
                                                 W1, Wsk02, W2, Wsk13, W3, wt);
    bin_scan_init<<<1, MAXCB, 0, stream>>>(gcnt, ncb, cbase, gcur1);
    scatter_coarse<<<cdiv(e, TILE1), SCAT_T, 0, stream>>>(ei, e, cshift, gcur1, gpk1);
    bucket_build_coarse<<<ncb, 1024, 0, stream>>>(gpk1, cbase, cshift, n, e,
                                                  dinv, row_ptr, col);

    // GEMM A (MFMA): preb = (x@W1)*dinv fp16, sk02 = x@Wsk02 fp16
    gemm_mfma<128, 64, 32, false><<<cdiv(n, 64), 256, 0, stream>>>(
        x, wt, dinv, preb, sk02, n);
    // layer 1: h1 = relu(conv(x,W1,b1))  (fp16) — wave-based
    gather_combine<64, true><<<cdiv(n, 4), 256, 0, stream>>>(
        (const uint4*)preb, row_ptr, col, dinv, b1, h1, n);

    // GEMM B (MFMA, fp16 A): preb = (h1@W2)*dinv, sk13 = h1@Wsk13 fp16
    gemm_mfma<64, 32, 16, true><<<cdiv(n, 64), 256, 0, stream>>>(
        h1, wt + 12288, dinv, preb, sk13, n);
    // layer 2: h2 = relu(conv(h1,W2,b2) + x@Wsk02 + bsk02)  (fp16) — 8 threads/node
    gather_tpn<32, 8, false, true><<<cdiv(n, 32), 256, 0, stream>>>(
        (const uint4*)preb, row_ptr, col, dinv, b2, (const uint4*)sk02, bsk02,
        h2, nullptr, nullptr, n);

    // GEMM C (MFMA, fp16 A): preb = (h2@W3)*dinv
    gemm_mfma<32, 16, 0, true><<<cdiv(n, 64), 256, 0, stream>>>(
        h2, wt + 15360, dinv, preb, sk13, n);
    // layer 3 + head — 8 threads/node
    gather_tpn<16, 8, true, false><<<cdiv(n, 32), 256, 0, stream>>>(
        (const uint4*)preb, row_ptr, col, dinv, b3, (const uint4*)sk13, bsk13,
        d_out, Wlin, blin, n);
}

// Round 19
// 448.492 us; speedup vs baseline: 1.0669x; 1.0669x over previous
//
#include <hip/hip_runtime.h>
#include <hip/hip_fp16.h>
#include <math.h>

// Bucketed CSR build tunables.
#define MAXB 1024        // max fine buckets in LDS arrays
#define MAXCB 128        // max coarse buckets
#define TILE1 8192       // edges per scatter tile
#define SCAT_T 512
#define EPT1 (TILE1 / SCAT_T)
#define LCAP 13568       // bucket_build LDS col capacity
#define GCHUNK 4096      // gather_tpn col-chunk (16 KB LDS)

typedef _Float16 f16x8 __attribute__((ext_vector_type(8)));
typedef float f32x4 __attribute__((ext_vector_type(4)));

// ---------------- fp16 pack helpers ----------------

__device__ __forceinline__ unsigned int pack_f16(float a, float b) {
    __half2 h = __floats2half2_rn(a, b);
    return *reinterpret_cast<unsigned int*>(&h);
}
__device__ __forceinline__ float f16_lo(unsigned int u) {
    __half2 h = *reinterpret_cast<__half2*>(&u);
    return __low2float(h);
}
__device__ __forceinline__ float f16_hi(unsigned int u) {
    __half2 h = *reinterpret_cast<__half2*>(&u);
    return __high2float(h);
}
__device__ __forceinline__ void acc8(float* a, uint4 u) {
    a[0] += f16_lo(u.x); a[1] += f16_hi(u.x);
    a[2] += f16_lo(u.y); a[3] += f16_hi(u.y);
    a[4] += f16_lo(u.z); a[5] += f16_hi(u.z);
    a[6] += f16_lo(u.w); a[7] += f16_hi(u.w);
}
__device__ __forceinline__ void unpack8(uint4 u, float* v) {
    v[0] = f16_lo(u.x); v[1] = f16_hi(u.x);
    v[2] = f16_lo(u.y); v[3] = f16_hi(u.y);
    v[4] = f16_lo(u.z); v[5] = f16_hi(u.z);
    v[6] = f16_lo(u.w); v[7] = f16_hi(u.w);
}
__device__ __forceinline__ uint4 h2add4(uint4 a, uint4 b) {
    const __half2* pa = reinterpret_cast<const __half2*>(&a);
    const __half2* pb = reinterpret_cast<const __half2*>(&b);
    uint4 r;
    __half2* pr = reinterpret_cast<__half2*>(&r);
#pragma unroll
    for (int i = 0; i < 4; i++) pr[i] = __hadd2(pa[i], pb[i]);
    return r;
}
__device__ __forceinline__ unsigned int pkadd(unsigned int a, unsigned int b) {
    __half2 r = __hadd2(*reinterpret_cast<__half2*>(&a), *reinterpret_cast<__half2*>(&b));
    return *reinterpret_cast<unsigned int*>(&r);
}

// ---------------- inline edge dtype detection (int32 vs int64) ----------------

__device__ __forceinline__ bool detect64(const int* __restrict__ ei) {
    int lane = threadIdx.x & 63;
    unsigned long long m = __ballot(ei[2 * lane + 1] != 0);
    return m == 0ull;
}

__device__ __forceinline__ int load_src(const int* ei, int e, bool is64, int i) {
    return is64 ? ei[2 * i] : ei[i];
}
__device__ __forceinline__ int load_dst(const int* ei, int e, bool is64, int i) {
    return is64 ? ei[2 * e + 2 * i] : ei[e + i];
}

// ---------------- pass 1: per-fine-bucket edge counts ----------------

__global__ __launch_bounds__(256) void bin_count(const int* __restrict__ ei, int e,
                                                 int shift, int* __restrict__ gcnt) {
    __shared__ int h[MAXB];
    for (int i = threadIdx.x; i < MAXB; i += 256) h[i] = 0;
    bool is64 = detect64(ei);
    __syncthreads();
    int stride = gridDim.x * 256;
    for (int i = blockIdx.x * 256 + threadIdx.x; i < e; i += stride) {
        int d = load_dst(ei, e, is64, i);
        atomicAdd(&h[d >> shift], 1);
    }
    __syncthreads();
    for (int i = threadIdx.x; i < MAXB; i += 256)
        if (h[i]) atomicAdd(&gcnt[i], h[i]);
}

// ---------------- pass 2: scan fine counts; init fine + coarse cursors ----------

__global__ void bin_scan_init(const int* __restrict__ gcnt, int nb, int ncb,
                              int* __restrict__ base, int* __restrict__ gcursor,
                              int* __restrict__ gcur1) {
    __shared__ int sh[1024];
    __shared__ int ex[1024];
    int t = threadIdx.x;
    int v = (t < nb) ? gcnt[t] : 0;
    sh[t] = v;
    __syncthreads();
    for (int off = 1; off < 1024; off <<= 1) {
        int x = (t >= off) ? sh[t - off] : 0;
        __syncthreads();
        sh[t] += x;
        __syncthreads();
    }
    int excl = sh[t] - v;
    ex[t] = excl;
    if (t < nb) {
        base[t] = excl;
        gcursor[t] = excl;
        if (t == nb - 1) base[nb] = sh[t];
    }
    __syncthreads();
    if (t < ncb) gcur1[t] = ex[8 * t];
}

// ---------------- pass 3a: coarse scatter ----------------

__global__ __launch_bounds__(SCAT_T) void scatter_coarse(const int* __restrict__ ei, int e,
                                                         int shift,
                                                         int* __restrict__ gcur1,
                                                         unsigned int* __restrict__ gpk1) {
    __shared__ int hist[MAXCB];
    __shared__ int lbase[MAXCB];
    __shared__ int delta[MAXCB];
    __shared__ int cur[MAXCB];
    __shared__ unsigned int sbuf[TILE1];
    __shared__ unsigned char sbkt[TILE1];
    __shared__ int sh[SCAT_T];

    const int t = threadIdx.x;
    const int pkshift = shift + 3;
    const int pkmask = (1 << pkshift) - 1;
    const bool is64 = detect64(ei);
    const int tile0 = blockIdx.x * TILE1;
    const int cnt = min(TILE1, e - tile0);

    for (int i = t; i < MAXCB; i += SCAT_T) hist[i] = 0;
    __syncthreads();

    unsigned int pk[EPT1];
    int bk[EPT1];
#pragma unroll
    for (int k = 0; k < EPT1; k++) {
        int g = tile0 + k * SCAT_T + t;
        bk[k] = -1;
        if (g < e) {
            int s = load_src(ei, e, is64, g);
            int d = load_dst(ei, e, is64, g);
            pk[k] = ((unsigned int)s << pkshift) | (unsigned int)(d & pkmask);
            bk[k] = d >> pkshift;
            atomicAdd(&hist[bk[k]], 1);
        }
    }
    __syncthreads();

    {
        int v = (t < MAXCB) ? hist[t] : 0;
        sh[t] = v;
        __syncthreads();
        for (int off = 1; off < SCAT_T; off <<= 1) {
            int x = (t >= off) ? sh[t - off] : 0;
            __syncthreads();
            sh[t] += x;
            __syncthreads();
        }
        if (t < MAXCB) lbase[t] = sh[t] - v;
    }
    __syncthreads();

    if (t < MAXCB) {
        int c = hist[t];
        if (c > 0) delta[t] = atomicAdd(&gcur1[t], c) - lbase[t];
        cur[t] = lbase[t];
    }
    __syncthreads();

#pragma unroll
    for (int k = 0; k < EPT1; k++) {
        if (bk[k] >= 0) {
            int p = atomicAdd(&cur[bk[k]], 1);
            sbuf[p] = pk[k];
            sbkt[p] = (unsigned char)bk[k];
        }
    }
    __syncthreads();

    for (int i = t; i < cnt; i += SCAT_T)
        gpk1[delta[sbkt[i]] + i] = sbuf[i];
}

// ---------------- pass 3b: fine scatter within coarse buckets ----------------

__global__ __launch_bounds__(SCAT_T) void scatter_fine(const unsigned int* __restrict__ gpk1,
                                                       const int* __restrict__ base,
                                                       int nbkt, int shift,
                                                       int* __restrict__ gcursor,
                                                       unsigned int* __restrict__ gpk2) {
    __shared__ int hist[8];
    __shared__ int lbase[8];
    __shared__ int delta[8];
    __shared__ int cur[8];
    __shared__ unsigned int sbuf[TILE1];
    __shared__ unsigned char sbkt[TILE1];

    const int t = threadIdx.x;
    const int cb = blockIdx.x >> 3;
    const int s = blockIdx.x & 7;
    const int f0 = 8 * cb;
    const int fhiIdx = min(f0 + 8, nbkt);
    const int lo = base[f0];
    const int hi = base[fhiIdx];
    const int len = hi - lo;
    const int slo = lo + (int)((long long)len * s / 8);
    const int shi = lo + (int)((long long)len * (s + 1) / 8);

    for (int tile0 = slo; tile0 < shi; tile0 += TILE1) {
        const int cnt = min(TILE1, shi - tile0);
        if (t < 8) hist[t] = 0;
        __syncthreads();

        unsigned int pk[EPT1];
        int bk[EPT1];
#pragma unroll
        for (int k = 0; k < EPT1; k++) {
            int li = k * SCAT_T + t;
            bk[k] = -1;
            if (li < cnt) {
                pk[k] = gpk1[tile0 + li];
                bk[k] = (pk[k] >> shift) & 7;
                atomicAdd(&hist[bk[k]], 1);
            }
        }
        __syncthreads();

        if (t == 0) {
            int run = 0;
            for (int f = 0; f < 8; f++) { lbase[f] = run; run += hist[f]; }
        }
        __syncthreads();
        if (t < 8) {
            int c = hist[t];
            if (c > 0) delta[t] = atomicAdd(&gcursor[f0 + t], c) - lbase[t];
            cur[t] = lbase[t];
        }
        __syncthreads();

#pragma unroll
        for (int k = 0; k < EPT1; k++) {
            if (bk[k] >= 0) {
                int p = atomicAdd(&cur[bk[k]], 1);
                sbuf[p] = pk[k];
                sbkt[p] = (unsigned char)bk[k];
            }
        }
        __syncthreads();

        for (int i = t; i < cnt; i += SCAT_T)
            gpk2[delta[sbkt[i]] + i] = sbuf[i];
        __syncthreads();
    }
}

// ---------------- pass 4: fused dinv + row_ptr + CSR col ----------------

__global__ __launch_bounds__(256) void bucket_build(const unsigned int* __restrict__ gpk,
                                                    const int* __restrict__ base, int shift,
                                                    int n, int e, float* __restrict__ dinv,
                                                    int* __restrict__ row_ptr,
                                                    int* __restrict__ col) {
    __shared__ int lcol[LCAP];
    __shared__ int dc[MAXB];
    __shared__ int cur[MAXB];
    __shared__ int sh[256];
    const int t = threadIdx.x;
    const int b = blockIdx.x;
    const int pkshift = shift + 3;
    const int mask = (1 << shift) - 1;
    const int width = 1 << shift;
    const int node0 = b << shift;
    const int nc = min(width, n - node0);
    const int lo = base[b], hi = base[b + 1];
    const int ecnt = hi - lo;

    for (int i = t; i < width; i += 256) dc[i] = 0;
    __syncthreads();
    for (int j = lo + t; j < hi; j += 256)
        atomicAdd(&dc[gpk[j] & mask], 1);
    __syncthreads();
    {
        int b4 = t * 4;
        int v0 = (b4 + 0 < width) ? dc[b4 + 0] : 0;
        int v1 = (b4 + 1 < width) ? dc[b4 + 1] : 0;
        int v2 = (b4 + 2 < width) ? dc[b4 + 2] : 0;
        int v3 = (b4 + 3 < width) ? dc[b4 + 3] : 0;
        int s = v0 + v1 + v2 + v3;
        sh[t] = s;
        __syncthreads();
        for (int off = 1; off < 256; off <<= 1) {
            int x = (t >= off) ? sh[t - off] : 0;
            __syncthreads();
            sh[t] += x;
            __syncthreads();
        }
        int excl = sh[t] - s;
        int pf[4] = {excl, excl + v0, excl + v0 + v1, excl + v0 + v1 + v2};
        int vv[4] = {v0, v1, v2, v3};
#pragma unroll
        for (int q = 0; q < 4; q++) {
            int i = b4 + q;
            if (i < nc) {
                row_ptr[node0 + i] = lo + pf[q];
                dinv[node0 + i] = rsqrtf(1.0f + (float)vv[q]);
            }
            if (i < width) cur[i] = pf[q];
        }
    }
    if (b == gridDim.x - 1 && t == 0) row_ptr[n] = e;
    __syncthreads();

    if (ecnt <= LCAP) {
        for (int j = lo + t; j < hi; j += 256) {
            unsigned int v = gpk[j];
            int p = atomicAdd(&cur[v & mask], 1);
            lcol[p] = (int)(v >> pkshift);
        }
        __syncthreads();
        for (int j = t; j < ecnt; j += 256)
            col[lo + j] = lcol[j];
    } else {
        for (int j = lo + t; j < hi; j += 256) {
            unsigned int v = gpk[j];
            int p = atomicAdd(&cur[v & mask], 1);
            col[lo + p] = (int)(v >> pkshift);
        }
    }
}

// ---------------- one-shot weight transpose+convert: W^T fp16 ----------------

__global__ void prep_w(const float* __restrict__ W1, const float* __restrict__ Wsk02,
                       const float* __restrict__ W2, const float* __restrict__ Wsk13,
                       const float* __restrict__ W3, unsigned short* __restrict__ wt) {
    int i = blockIdx.x * 256 + threadIdx.x;
    float v;
    if (i < 12288) {
        int c = i >> 7, k = i & 127;
        v = (c < 64) ? W1[k * 64 + c] : Wsk02[k * 32 + (c - 64)];
    } else if (i < 15360) {
        int j = i - 12288;
        int c = j >> 6, k = j & 63;
        v = (c < 32) ? W2[k * 32 + c] : Wsk13[k * 16 + (c - 32)];
    } else if (i < 15872) {
        int j = i - 15360;
        int c = j >> 5, k = j & 31;
        v = W3[k * 16 + c];
    } else return;
    wt[i] = (unsigned short)pack_f16(v, 0.f);
}

// ---------------- MFMA GEMM (fp16-packed out1/out2) ----------------

template <int K, int CO1, int CO2, bool AHALF>
__global__ __launch_bounds__(256) void gemm_mfma(const void* __restrict__ Av,
                                                 const unsigned short* __restrict__ wt,
                                                 const float* __restrict__ dinv,
                                                 unsigned int* __restrict__ out1,
                                                 unsigned int* __restrict__ out2, int n) {
    constexpr int N = CO1 + CO2;
    constexpr int NCT = N / 16;
    constexpr int NK = K / 32;
    constexpr int CHK = K / 8;
    constexpr int SWZ = (CHK - 1) < 15 ? (CHK - 1) : 15;
    __shared__ __align__(16) unsigned char Ash[64 * K * 2];
    __shared__ __align__(16) unsigned char Bsh[N * K * 2];

    const int t = threadIdx.x;
    const int row0 = blockIdx.x * 64;

    for (int i = t; i < 64 * CHK; i += 256) {
        int r = i / CHK, c = i % CHK;
        int row = row0 + r;
        uint4 w{0u, 0u, 0u, 0u};
        if (row < n) {
            if (AHALF) {
                w = *reinterpret_cast<const uint4*>(
                    (const unsigned short*)Av + (size_t)row * K + c * 8);
            } else {
                const float* xr = (const float*)Av + (size_t)row * K + c * 8;
                float4 p = *reinterpret_cast<const float4*>(xr);
                float4 q = *reinterpret_cast<const float4*>(xr + 4);
                w.x = pack_f16(p.x, p.y); w.y = pack_f16(p.z, p.w);
                w.z = pack_f16(q.x, q.y); w.w = pack_f16(q.z, q.w);
            }
        }
        int addr = i * 16;
        addr ^= ((r & SWZ) << 4);
        *reinterpret_cast<uint4*>(&Ash[addr]) = w;
    }
    for (int i = t; i < N * CHK; i += 256) {
        int cc = i / CHK;
        uint4 w = *reinterpret_cast<const uint4*>(&wt[(i / CHK) * K + (i % CHK) * 8]);
        int addr = i * 16;
        addr ^= ((cc & SWZ) << 4);
        *reinterpret_cast<uint4*>(&Bsh[addr]) = w;
    }
    __syncthreads();

    const int wv = t >> 6;
    const int lane = t & 63;
    const int lrow = wv * 16 + (lane & 15);
    const int kb = (lane >> 4) * 16;

    f16x8 afr[NK];
#pragma unroll
    for (int s = 0; s < NK; s++) {
        int addr = lrow * (2 * K) + s * 64 + kb;
        addr ^= ((lrow & SWZ) << 4);
        afr[s] = *reinterpret_cast<const f16x8*>(&Ash[addr]);
    }

    f32x4 acc[NCT];
#pragma unroll
    for (int ct = 0; ct < NCT; ct++) acc[ct] = f32x4{0.f, 0.f, 0.f, 0.f};

#pragma unroll
    for (int ct = 0; ct < NCT; ct++) {
        int cc = ct * 16 + (lane & 15);
#pragma unroll
        for (int s = 0; s < NK; s++) {
            int addr = cc * (2 * K) + s * 64 + kb;
            addr ^= ((cc & SWZ) << 4);
            f16x8 bfr = *reinterpret_cast<const f16x8*>(&Bsh[addr]);
            acc[ct] = __builtin_amdgcn_mfma_f32_16x16x32_f16(afr[s], bfr, acc[ct], 0, 0, 0);
        }
    }

    const int rbase = row0 + wv * 16 + (lane >> 4) * 4;
    const int cidx = lane & 15;
    float dn[4];
#pragma unroll
    for (int r = 0; r < 4; r++) dn[r] = (rbase + r < n) ? dinv[rbase + r] : 0.f;

#pragma unroll
    for (int ct = 0; ct < NCT; ct++) {
        int col = ct * 16 + cidx;
        if (col < CO1) {
#pragma unroll
            for (int r = 0; r < 4; r++) {
                float v = acc[ct][r] * dn[r];
                float o = __shfl_xor(v, 1);
                int row = rbase + r;
                if (!(lane & 1) && row < n)
                    out1[(size_t)row * (CO1 / 2) + ct * 8 + cidx / 2] = pack_f16(v, o);
            }
        } else if (CO2 > 0) {
#pragma unroll
            for (int r = 0; r < 4; r++) {
                float v = acc[ct][r];
                float o = __shfl_xor(v, 1);
                int row = rbase + r;
                if (!(lane & 1) && row < n)
                    out2[(size_t)row * (CO2 / 2) + (ct * 16 + cidx - CO1) / 2] =
                        pack_f16(v, o);
            }
        }
    }
}

// ---------------- Wave-based gather for F=64 (at fabric floor) ----------------

template <int F, bool PACKOUT>
__global__ __launch_bounds__(256) void gather_combine(
    const uint4* __restrict__ hp4, const int* __restrict__ row_ptr,
    const int* __restrict__ col, const float* __restrict__ dinv,
    const float* __restrict__ bias, void* __restrict__ outv, int n) {
    constexpr int L = F / 8;
    constexpr int EPW = 64 / L;
    int wid = (blockIdx.x * blockDim.x + threadIdx.x) >> 6;
    int lane = threadIdx.x & 63;
    if (wid >= n) return;
    int s = lane / L;
    int el = lane % L;
    int start = row_ptr[wid];
    int end = row_ptr[wid + 1];

    float a[8] = {0.f, 0.f, 0.f, 0.f, 0.f, 0.f, 0.f, 0.f};
    const uint4 z4{0u, 0u, 0u, 0u};
    for (int j = start + s; j < end; j += 4 * EPW) {
        int j1 = j + EPW, j2 = j + 2 * EPW, j3 = j + 3 * EPW;
        bool v1 = j1 < end, v2 = j2 < end, v3 = j3 < end;
        int c0 = col[j];
        int c1 = col[v1 ? j1 : j];
        int c2 = col[v2 ? j2 : j];
        int c3 = col[v3 ? j3 : j];
        uint4 u0 = hp4[(size_t)c0 * L + el];
        uint4 u1 = hp4[(size_t)c1 * L + el];
        uint4 u2 = hp4[(size_t)c2 * L + el];
        uint4 u3 = hp4[(size_t)c3 * L + el];
        if (!v1) u1 = z4;
        if (!v2) u2 = z4;
        if (!v3) u3 = z4;
        uint4 t01 = h2add4(u0, u1);
        uint4 t23 = h2add4(u2, u3);
        acc8(a, h2add4(t01, t23));
    }

#pragma unroll
    for (int m = L; m < 64; m <<= 1) {
#pragma unroll
        for (int q = 0; q < 8; q++) a[q] += __shfl_xor(a[q], m);
    }

    if (lane < L) {
        float dn = dinv[wid];
        uint4 us = hp4[(size_t)wid * L + el];
        float v[8];
        unpack8(us, v);
        float4 b0 = *reinterpret_cast<const float4*>(&bias[8 * el]);
        float4 b1 = *reinterpret_cast<const float4*>(&bias[8 * el + 4]);
        float o[8];
        o[0] = dn * a[0] + v[0] * dn + b0.x;
        o[1] = dn * a[1] + v[1] * dn + b0.y;
        o[2] = dn * a[2] + v[2] * dn + b0.z;
        o[3] = dn * a[3] + v[3] * dn + b0.w;
        o[4] = dn * a[4] + v[4] * dn + b1.x;
        o[5] = dn * a[5] + v[5] * dn + b1.y;
        o[6] = dn * a[6] + v[6] * dn + b1.z;
        o[7] = dn * a[7] + v[7] * dn + b1.w;
#pragma unroll
        for (int q = 0; q < 8; q++) o[q] = fmaxf(o[q], 0.f);
        if (PACKOUT) {
            uint4 pk{pack_f16(o[0], o[1]), pack_f16(o[2], o[3]),
                     pack_f16(o[4], o[5]), pack_f16(o[6], o[7])};
            ((uint4*)outv)[(size_t)wid * L + el] = pk;
        } else {
            float* out = (float*)outv;
            float4 w0{o[0], o[1], o[2], o[3]};
            float4 w1{o[4], o[5], o[6], o[7]};
            *reinterpret_cast<float4*>(&out[(size_t)wid * F + 8 * el]) = w0;
            *reinterpret_cast<float4*>(&out[(size_t)wid * F + 8 * el + 4]) = w1;
        }
    }
}

// ---------------- Multi-thread-per-node gather for F=16/32 (T=8, fp16 sk) ----------

template <int F, int T, bool FINAL, bool PACKOUT>
__global__ __launch_bounds__(256) void gather_tpn(
    const uint4* __restrict__ hp4, const int* __restrict__ row_ptr,
    const int* __restrict__ col, const float* __restrict__ dinv,
    const float* __restrict__ bias, const uint4* __restrict__ skh,
    const float* __restrict__ bsk, void* __restrict__ outv,
    const float* __restrict__ Wlin, const float* __restrict__ blin, int n) {
    constexpr int L = F / 8;       // uint4 words per row
    constexpr int NPB = 256 / T;   // nodes per block
    __shared__ int lcol[GCHUNK];
    const int t = threadIdx.x;
    const int sub = t & (T - 1);
    const int node0 = blockIdx.x * NPB;
    const int node = node0 + (t / T);
    const int hiN = min(node0 + NPB, n);
    const int lo = row_ptr[node0];
    const int hi = row_ptr[hiN];

    int start = 0, end = 0;
    if (node < n) { start = row_ptr[node]; end = row_ptr[node + 1]; }

    unsigned int acc[F / 2];
#pragma unroll
    for (int q = 0; q < F / 2; q++) acc[q] = 0u;

    for (int ch = lo; ch < hi; ch += GCHUNK) {
        int cnt = min(GCHUNK, hi - ch);
        __syncthreads();
        for (int i = t; i < cnt; i += 256) lcol[i] = col[ch + i];
        __syncthreads();
        int first = start + sub;
        if (first < ch) first += ((ch - first + T - 1) & ~(T - 1));
        int last = min(end, ch + cnt);
        int j = first;
        if (j < last) {
            uint4 u[L];
            {
                const uint4* rp = hp4 + (size_t)lcol[j - ch] * L;
#pragma unroll
                for (int w = 0; w < L; w++) u[w] = rp[w];
            }
            for (j += T; j < last; j += T) {
                uint4 v[L];
                const uint4* rq = hp4 + (size_t)lcol[j - ch] * L;
#pragma unroll
                for (int w = 0; w < L; w++) v[w] = rq[w];   // next row in flight
#pragma unroll
                for (int w = 0; w < L; w++) {
                    acc[4 * w + 0] = pkadd(acc[4 * w + 0], u[w].x);
                    acc[4 * w + 1] = pkadd(acc[4 * w + 1], u[w].y);
                    acc[4 * w + 2] = pkadd(acc[4 * w + 2], u[w].z);
                    acc[4 * w + 3] = pkadd(acc[4 * w + 3], u[w].w);
                }
#pragma unroll
                for (int w = 0; w < L; w++) u[w] = v[w];
            }
#pragma unroll
            for (int w = 0; w < L; w++) {
                acc[4 * w + 0] = pkadd(acc[4 * w + 0], u[w].x);
                acc[4 * w + 1] = pkadd(acc[4 * w + 1], u[w].y);
                acc[4 * w + 2] = pkadd(acc[4 * w + 2], u[w].z);
                acc[4 * w + 3] = pkadd(acc[4 * w + 3], u[w].w);
            }
        }
    }

    // combine the T sub-thread partials
#pragma unroll
    for (int m = 1; m < T; m <<= 1) {
#pragma unroll
        for (int q = 0; q < F / 2; q++) {
            unsigned int o = (unsigned int)__shfl_xor((int)acc[q], m);
            acc[q] = pkadd(acc[q], o);
        }
    }

    if (node < n && sub == 0) {
        float dn = dinv[node];
        const uint4* sp = hp4 + (size_t)node * L;
        float o[F];
#pragma unroll
        for (int w = 0; w < L; w++) {
            uint4 u = sp[w];
            float sv[8];
            unpack8(u, sv);
#pragma unroll
            for (int q = 0; q < 8; q++) {
                int f = w * 8 + q;
                float av = (q & 1) ? f16_hi(acc[4 * w + (q >> 1)])
                                   : f16_lo(acc[4 * w + (q >> 1)]);
                o[f] = dn * (av + sv[q]) + bias[f];
            }
        }
        if (skh) {
            const uint4* skp = skh + (size_t)node * L;
#pragma unroll
            for (int w = 0; w < L; w++) {
                float sv2[8];
                unpack8(skp[w], sv2);
#pragma unroll
                for (int q = 0; q < 8; q++)
                    o[w * 8 + q] += sv2[q] + bsk[w * 8 + q];
            }
        }
#pragma unroll
        for (int f = 0; f < F; f++) o[f] = fmaxf(o[f], 0.f);

        if (FINAL) {
            float d = blin[0];
#pragma unroll
            for (int f = 0; f < F; f++) d += o[f] * Wlin[f];
            ((float*)outv)[node] = 1.0f / (1.0f + expf(-d));
        } else if (PACKOUT) {
            uint4* o4 = (uint4*)outv + (size_t)node * L;
#pragma unroll
            for (int w = 0; w < L; w++) {
                uint4 pk{pack_f16(o[w * 8 + 0], o[w * 8 + 1]),
                         pack_f16(o[w * 8 + 2], o[w * 8 + 3]),
                         pack_f16(o[w * 8 + 4], o[w * 8 + 5]),
                         pack_f16(o[w * 8 + 6], o[w * 8 + 7])};
                o4[w] = pk;
            }
        }
    }
}

// ---------------- launch ----------------

extern "C" void kernel_launch(void* const* d_in, const int* in_sizes, int n_in,
                              void* d_out, int out_size, void* d_ws, size_t ws_size,
                              hipStream_t stream) {
    const float* x     = (const float*)d_in[0];
    const int*   ei    = (const int*)d_in[1];
    const float* W1    = (const float*)d_in[2];
    const float* b1    = (const float*)d_in[3];
    const float* W2    = (const float*)d_in[4];
    const float* b2    = (const float*)d_in[5];
    const float* W3    = (const float*)d_in[6];
    const float* b3    = (const float*)d_in[7];
    const float* Wsk02 = (const float*)d_in[8];
    const float* bsk02 = (const float*)d_in[9];
    const float* Wsk13 = (const float*)d_in[10];
    const float* bsk13 = (const float*)d_in[11];
    const float* Wlin  = (const float*)d_in[12];
    const float* blin  = (const float*)d_in[13];

    const int n = in_sizes[0] / 128;
    const int e = in_sizes[1] / 2;

    int shift = 8;
    while (((n + (1 << shift) - 1) >> shift) > MAXB) shift++;
    const int nbkt = (n + (1 << shift) - 1) >> shift;
    const int ncb = (nbkt + 7) / 8;

    // workspace carve (256B aligned)
    char* p = (char*)d_ws;
    auto alloc = [&](size_t bytes) {
        void* r = (void*)p;
        p += (bytes + 255) / 256 * 256;
        return r;
    };
    int*   gcnt    = (int*)alloc(MAXB * 4);
    int*   base    = (int*)alloc((MAXB + 1) * 4);
    int*   gcursor = (int*)alloc(MAXB * 4);
    int*   gcur1   = (int*)alloc(MAXCB * 4);
    unsigned short* wt = (unsigned short*)alloc(15872 * 2);
    int*   row_ptr = (int*)alloc((size_t)(n + 1) * 4);
    float* dinv    = (float*)alloc((size_t)n * 4);
    int*   col     = (int*)alloc((size_t)e * 4);
    size_t h1b     = (size_t)e * 4 > (size_t)n * 128 ? (size_t)e * 4 : (size_t)n * 128;
    unsigned int* h1 = (unsigned int*)alloc(h1b);
    unsigned int* h2 = (unsigned int*)alloc((size_t)n * 64);
    unsigned int* sk02 = (unsigned int*)alloc((size_t)n * 64);   // fp16 x@Wsk02
    unsigned int* sk13 = (unsigned int*)alloc((size_t)n * 32);   // fp16 h1@Wsk13
    size_t prebytes = (size_t)e * 4 > (size_t)n * 128 ? (size_t)e * 4 : (size_t)n * 128;
    unsigned int* preb = (unsigned int*)alloc(prebytes);
    unsigned int* gpk1 = h1;
    unsigned int* gpk2 = preb;

    auto cdiv = [](int a, int b) { return (a + b - 1) / b; };

    // weight prep (independent)
    prep_w<<<62, 256, 0, stream>>>(W1, Wsk02, W2, Wsk13, W3, wt);

    // CSR build
    hipMemsetAsync(gcnt, 0, MAXB * 4, stream);
    bin_count<<<1024, 256, 0, stream>>>(ei, e, shift, gcnt);
    bin_scan_init<<<1, 1024, 0, stream>>>(gcnt, nbkt, ncb, base, gcursor, gcur1);
    scatter_coarse<<<cdiv(e, TILE1), SCAT_T, 0, stream>>>(ei, e, shift, gcur1, gpk1);
    scatter_fine<<<ncb * 8, SCAT_T, 0, stream>>>(gpk1, base, nbkt, shift, gcursor, gpk2);
    bucket_build<<<nbkt, 256, 0, stream>>>(gpk2, base, shift, n, e, dinv, row_ptr, col);

    // GEMM A (MFMA): preb = (x@W1)*dinv fp16, sk02 = x@Wsk02 fp16
    gemm_mfma<128, 64, 32, false><<<cdiv(n, 64), 256, 0, stream>>>(
        x, wt, dinv, preb, sk02, n);
    // layer 1: h1 = relu(conv(x,W1,b1))  (fp16) — wave-based
    gather_combine<64, true><<<cdiv(n, 4), 256, 0, stream>>>(
        (const uint4*)preb, row_ptr, col, dinv, b1, h1, n);

    // GEMM B (MFMA, fp16 A): preb = (h1@W2)*dinv, sk13 = h1@Wsk13 fp16
    gemm_mfma<64, 32, 16, true><<<cdiv(n, 64), 256, 0, stream>>>(
        h1, wt + 12288, dinv, preb, sk13, n);
    // layer 2: h2 = relu(conv(h1,W2,b2) + x@Wsk02 + bsk02)  (fp16) — 8 threads/node
    gather_tpn<32, 8, false, true><<<cdiv(n, 32), 256, 0, stream>>>(
        (const uint4*)preb, row_ptr, col, dinv, b2, (const uint4*)sk02, bsk02,
        h2, nullptr, nullptr, n);

    // GEMM C (MFMA, fp16 A): preb = (h2@W3)*dinv
    gemm_mfma<32, 16, 0, true><<<cdiv(n, 64), 256, 0, stream>>>(
        h2, wt + 15360, dinv, preb, sk13, n);
    // layer 3 + head — 8 threads/node
    gather_tpn<16, 8, true, false><<<cdiv(n, 32), 256, 0, stream>>>(
        (const uint4*)preb, row_ptr, col, dinv, b3, (const uint4*)sk13, bsk13,
        d_out, Wlin, blin, n);
}